// Round 5
// baseline (234.854 us; speedup 1.0000x reference)
//
#include <hip/hip_runtime.h>
#include <math.h>

// ============================================================================
// WaveletBasis as bf16 MFMA GEMM: M=32768(B), N=64(O), K=1024*9.
// Aligned run layout: 128 runs of 72 k-values, run R = features [8R,8R+8).
// Run = 9 qslots: qslot f<8 = basis n=0..7 of feature 8R+f; qslot 8 = x-quad.
// Chunk c = runs [4c,4c+4) = 9 K32-steps. A tile (XOR-swizzled):
//   uint4 idx = qslot*256 + run_local*64 + (row ^ swz),
//   swz(qslot,run) = 2*run + (qslot>>2)   (bank-spreads scattered writes).
//
// ROUND 7: round 6 (role split) was FLAT at 84us. Re-audit: wall is memory
// pipes, not issue: (a) LDS 83K cyc/CU (A-read amp 2), (b) builder x loads
// uncoalesced (lane=row -> 64 lines/instr, ~30-60K cyc TA serialization),
// (c) B loads exposed ~300cyc L2 latency each chunk top. Fixes:
//  - builder lane remap (row=16b+8r+(l>>3), quad=l&7): x loads = 8x128B
//    contiguous segments; lane builds a half-run (4 features).
//  - MFMA waves = (mh row-half) x (ks step-parity), 32 rows x 64 cols:
//    A-read amp 1 (LDS 83K->55K); B amp 2 (ok, 1.15GB L2 total).
//  - A-tile XOR swizzle: scattered builder writes + reads both bank-even.
//  - B 3-deep rolling prefetch, compile-time slots; next chunk's first 3
//    frags issued BEFORE the barrier (barrier drains lgkmcnt only).
//  - epilogue reduction flat (f32x4 @ tid*4): conflict-free + coalesced.
// ============================================================================

typedef __attribute__((ext_vector_type(8))) short short8;
typedef __attribute__((ext_vector_type(4))) float f32x4;
typedef __attribute__((ext_vector_type(16))) float f32x16;

__device__ __forceinline__ unsigned int f2bf(float f) {
  unsigned int u = __float_as_uint(f);
  u += 0x7FFFu + ((u >> 16) & 1u);   // RNE; finite inputs
  return u >> 16;
}

// 4 dwords = 8 bf16 basis values (n=0..7) as a function of bucket j.
__device__ __forceinline__ void gen_basis(int j, unsigned int* d) {
  d[0] = (j < 4) ? 0x3F803F80u : 0xBF803F80u;                  // [phi=1, psi0=+-1]
  unsigned int sq1 = (j & 2) ? 0xBFB5u : 0x3FB5u;              // +-sqrt2
  d[1] = (j & 4) ? (sq1 << 16) : sq1;                          // one-hot k1=j>>2
  unsigned long long sd2 = (j & 1) ? 0xC000ull : 0x4000ull;    // +-2
  unsigned long long d23 = sd2 << ((j & 6) << 3);              // << 16*(j>>1)
  d[2] = (unsigned int)d23;
  d[3] = (unsigned int)(d23 >> 32);
}

#define BARRIER() __asm__ volatile("s_waitcnt lgkmcnt(0)\n\ts_barrier" ::: "memory")

// ---------------------------------------------------------------------------
// Builder: half-run (features 4h..4h+4 of run) for one row -> 4 basis quads
// + x-uint2, written at XOR-swizzled locations. Numerics unchanged
// (fast tanh + rare ref-fidelity fixer).
// ---------------------------------------------------------------------------
__device__ __forceinline__ void build_half(const float4& xq, uint4* __restrict__ buf,
                                           int run, int row, int h) {
  float xv[4] = {xq.x, xq.y, xq.z, xq.w};
  float t8v[4];
  unsigned int bad = 0;
#pragma unroll
  for (int ff = 0; ff < 4; ++ff) {
    float e = __expf(2.0f * xv[ff]);                 // t8 = 8*e/(e+1) = 8 - 8/(e+1)
    float r = __builtin_amdgcn_rcpf(e + 1.0f);
    float t8 = __builtin_fmaf(-8.0f, r, 8.0f);
    float rn = rintf(t8);
    if (fabsf(t8 - rn) < 3e-5f) bad |= 1u << ff;
    t8v[ff] = t8;
  }
  if (__builtin_expect(bad != 0, 0)) {
#pragma unroll
    for (int ff = 0; ff < 4; ++ff)
      if (bad & (1u << ff)) {
        float tf = (float)tanh((double)xv[ff]);      // ref-fidelity fallback
        t8v[ff] = ((tf + 1.0f) * 0.5f) * 8.0f;       // exact ref f32 pipeline
      }
  }
  // basis quads: qslot = 4h+k, swz = 2*run + h (qslot>>2 == h for k<4)
  uint4* dq = buf + run * 64 + (row ^ (2 * run + h));
#pragma unroll
  for (int k = 0; k < 4; ++k) {
    int j = (int)t8v[k]; j = j > 7 ? 7 : j;          // t8 in [0,8]
    unsigned int d[4];
    gen_basis(j, d);
    uint4 qv; qv.x = d[0]; qv.y = d[1]; qv.z = d[2]; qv.w = d[3];
    dq[(4 * h + k) * 256] = qv;
  }
  // x-quad (qslot 8): swz = 2*run + 2; this half's 2 dwords
  uint2 hv;
  hv.x = f2bf(xv[0]) | (f2bf(xv[1]) << 16);
  hv.y = f2bf(xv[2]) | (f2bf(xv[3]) << 16);
  uint4* dx = buf + 8 * 256 + run * 64 + (row ^ (2 * run + 2));
  ((uint2*)dx)[h] = hv;
}

// ---------------------------------------------------------------------------
// K1: W into 32x32x16 B-fragment order under the aligned run layout.
// Fragment (c,s,u,nq) at Bsw[((c*9+s)*4 + 2u + nq)*64 + l]: lane l holds
// col o = 32nq+(l&31), k = qslot s of run R = 4c+2u+(l>>5). Short jj:
// s<8 -> (f=8R+s, n=jj); s==8 -> (f=8R+jj, n=8 i.e. base_weight).
// ---------------------------------------------------------------------------
__global__ __launch_bounds__(256) void build_w(const float* __restrict__ coeffs,
                                               const float* __restrict__ bw,
                                               uint4* __restrict__ Wsw) {
  const int l = threadIdx.x & 63;
  const int t = threadIdx.x >> 6;   // t = 2u+nq, 0..3
  const int g = blockIdx.x;         // 0..287
  const int c = g / 9, j = g - c * 9;
  const int u = t >> 1, nq = t & 1;
  const int R = c * 4 + 2 * u + (l >> 5);
  const int o = nq * 32 + (l & 31);
  unsigned int dwv[4];
#pragma unroll
  for (int jj = 0; jj < 8; ++jj) {
    int f, n;
    if (j < 8) { f = 8 * R + j;  n = jj; }
    else       { f = 8 * R + jj; n = 8;  }
    float v = (n < 8) ? coeffs[(f * 64 + o) * 8 + n] : bw[f * 64 + o];
    unsigned int hh = f2bf(v);
    if (jj & 1) dwv[jj >> 1] |= hh << 16; else dwv[jj >> 1] = hh;
  }
  uint4 qq; qq.x = dwv[0]; qq.y = dwv[1]; qq.z = dwv[2]; qq.w = dwv[3];
  Wsw[(g * 4 + t) * 64 + l] = qq;
}

#define MFMA32(A, B, C) __builtin_amdgcn_mfma_f32_32x32x16_bf16( \
    __builtin_bit_cast(short8, (A)), __builtin_bit_cast(short8, (B)), (C), 0, 0, 0)

// ---------------------------------------------------------------------------
// MFMA-wave main loop: 32 rows (mh half) x 64 cols, steps s = ks, ks+2, ...
// Per step: 2 swizzle-corrected A ds_reads (u=0,1), 4 MFMAs.
// B: 3-deep rolling prefetch, compile-time slots; next chunk's first 3
// fragments issued before the end-of-chunk barrier (stay in flight).
// ---------------------------------------------------------------------------
template <int NS>
__device__ __forceinline__ void mfma_main(const uint4* __restrict__ Bsw,
                                          const uint4* __restrict__ Albuf,
                                          f32x16& acc0, f32x16& acc1,
                                          int ks, int mh, int l) {
  const int hi = l >> 5;
  const int l31 = l & 31;
  // per-(u, s>>2) lane offsets: run = 2u+hi, swz = 4u + 2hi + (s>>2)
  int offA[2][3];
#pragma unroll
  for (int u = 0; u < 2; ++u)
#pragma unroll
    for (int sd = 0; sd < 3; ++sd)
      offA[u][sd] = (2 * u + hi) * 64 + mh * 32 + (l31 ^ (4 * u + 2 * hi + sd));

  uint4 Bq[3][4];   // slot i%3: [u0nq0, u0nq1, u1nq0, u1nq1]
#pragma unroll
  for (int i = 0; i < 3; ++i) {
    const uint4* wp = Bsw + (size_t)((ks + 2 * i) * 4) * 64 + l;
    Bq[i][0] = wp[0]; Bq[i][1] = wp[64]; Bq[i][2] = wp[128]; Bq[i][3] = wp[192];
  }
  BARRIER();                                   // chunk 0 A ready
  for (int c = 0; c < 32; ++c) {
    const uint4* cur = Albuf + (c & 1) * 2304;
    __builtin_amdgcn_s_setprio(1);
#pragma unroll
    for (int i = 0; i < NS; ++i) {
      const int s = ks + 2 * i;
      const int sd = s >> 2;
      const uint4* rb = cur + s * 256;
      uint4 a0 = rb[offA[0][sd]];
      uint4 a1 = rb[offA[1][sd]];
      acc0 = MFMA32(a0, Bq[i % 3][0], acc0);
      acc1 = MFMA32(a0, Bq[i % 3][1], acc1);
      acc0 = MFMA32(a1, Bq[i % 3][2], acc0);
      acc1 = MFMA32(a1, Bq[i % 3][3], acc1);
      if (i + 3 < NS) {                        // in-chunk prefetch, slot i%3
        const uint4* wp = Bsw + (size_t)((c * 9 + ks + 2 * (i + 3)) * 4) * 64 + l;
        Bq[i % 3][0] = wp[0];   Bq[i % 3][1] = wp[64];
        Bq[i % 3][2] = wp[128]; Bq[i % 3][3] = wp[192];
      }
    }
    __builtin_amdgcn_s_setprio(0);
    // next chunk's first 3 steps -> slots 0,1,2 (all consumed); loads cross
    // the barrier in flight (BARRIER drains lgkmcnt only).
    if (c + 1 < 32) {
#pragma unroll
      for (int i = 0; i < 3; ++i) {
        const uint4* wp = Bsw + (size_t)(((c + 1) * 9 + ks + 2 * i) * 4) * 64 + l;
        Bq[i][0] = wp[0]; Bq[i][1] = wp[64]; Bq[i][2] = wp[128]; Bq[i][3] = wp[192];
      }
    }
    BARRIER();
  }
}

// ---------------------------------------------------------------------------
// K2: 512 blocks x 512 thr. Block = 64 rows x 64 cols.
// Waves 0-3: MFMA (mh = w>>1 row half, ks = w&1 step parity, NS=5/4).
// Waves 4-7: builders (b = w-4: rows [16b,16b+16), lane l -> row 16b+8r+
// (l>>3), quad l&7 -> run quad>>1, half quad&1) -- coalesced x loads.
// LDS: 2 x 36 KB A double-buffer; low 32 KB reused as 2 ks-partials at end.
// ---------------------------------------------------------------------------
__global__ __launch_bounds__(512, 4) void wavelet_gemm(const float* __restrict__ x,
                                                       const uint4* __restrict__ Bsw,
                                                       float* __restrict__ out,
                                                       int out_size) {
  __shared__ uint4 Albuf[2 * 9 * 256];   // 72 KB
  const int tid = threadIdx.x;
  const int l = tid & 63;
  const int w = tid >> 6;            // wave 0..7
  const long rowbase = (long)blockIdx.x * 64;
  float* P = (float*)Albuf;          // epilogue partials (32 KB, reused)

  if (w < 4) {
    // ---------------- MFMA waves ----------------
    const int mh = w >> 1;           // row half
    const int ks = w & 1;            // 0: steps {0,2,4,6,8}; 1: {1,3,5,7}
    f32x16 acc0 = {};                // cols 0..31 of the wave's 32-row half
    f32x16 acc1 = {};                // cols 32..63
    if (ks == 0) mfma_main<5>(Bsw, Albuf, acc0, acc1, 0, mh, l);
    else         mfma_main<4>(Bsw, Albuf, acc0, acc1, 1, mh, l);
    // ks-partial store: P[ks][row][col]; 32x32 C/D layout:
    // col=lane&31, row=(reg&3)+8*(reg>>2)+4*(lane>>5).
    float* Pk = P + ks * 4096;
    const int colb = l & 31;
    const int rb32 = mh * 32 + 4 * (l >> 5);
#pragma unroll
    for (int rg = 0; rg < 16; ++rg) {
      const int grow = (rg & 3) + 8 * (rg >> 2) + rb32;
      Pk[grow * 64 + colb]      = acc0[rg];
      Pk[grow * 64 + 32 + colb] = acc1[rg];
    }
    BARRIER();                       // partials visible
  } else {
    // ---------------- builder waves ----------------
    const int b = w - 4;             // rows [16b, 16b+16)
    const int quad = l & 7;
    const int run = quad >> 1, h = quad & 1;
    const int row0 = 16 * b + (l >> 3);
    const int row1 = row0 + 8;
    const float* xp0 = x + (rowbase + row0) * 1024 + quad * 4;
    const float* xp1 = x + (rowbase + row1) * 1024 + quad * 4;
    float4 xa0 = *(const float4*)(xp0);          // chunk 0
    float4 xa1 = *(const float4*)(xp1);
    build_half(xa0, Albuf, run, row0, h);
    build_half(xa1, Albuf, run, row1, h);
    xa0 = *(const float4*)(xp0 + 32);            // chunk 1
    xa1 = *(const float4*)(xp1 + 32);
    BARRIER();                       // chunk 0 ready
    for (int c = 0; c < 32; ++c) {
      if (c + 1 < 32) {
        uint4* nb = Albuf + ((c + 1) & 1) * 2304;
        build_half(xa0, nb, run, row0, h);
        build_half(xa1, nb, run, row1, h);
        if (c + 2 < 32) {
          xa0 = *(const float4*)(xp0 + (c + 2) * 32);
          xa1 = *(const float4*)(xp1 + (c + 2) * 32);
        }
      }
      BARRIER();
    }
    BARRIER();                       // wait for MFMA partials
  }

  // ---- joint reduction: out = P[0] + P[1], flat & conflict-free -----------
  float* og = out + (size_t)rowbase * 64;
  const int d = tid * 4;
  f32x4 v0 = *(const f32x4*)(P + d)        + *(const f32x4*)(P + 4096 + d);
  f32x4 v1 = *(const f32x4*)(P + 2048 + d) + *(const f32x4*)(P + 6144 + d);
  *(f32x4*)(og + d) = v0;
  *(f32x4*)(og + 2048 + d) = v1;
  if (blockIdx.x == 0 && tid == 0) out[out_size - 1] = 0.0f;  // kl = 0
}

extern "C" void kernel_launch(void* const* d_in, const int* in_sizes, int n_in,
                              void* d_out, int out_size, void* d_ws, size_t ws_size,
                              hipStream_t stream) {
  const float* x      = (const float*)d_in[0];   // [32768,1024] f32
  const float* coeffs = (const float*)d_in[1];   // [1024,64,8] f32
  const float* bw     = (const float*)d_in[2];   // [1024,64] f32
  uint4* Wsw = (uint4*)d_ws;                     // 288*4*64*16 = 1.125 MiB
  float* out = (float*)d_out;

  build_w<<<288, 256, 0, stream>>>(coeffs, bw, Wsw);
  wavelet_gemm<<<512, 512, 0, stream>>>(x, (const uint4*)Wsw, out, out_size);
}